// Round 2
// baseline (6656.939 us; speedup 1.0000x reference)
//
#include <hip/hip_runtime.h>

typedef unsigned short u16;
typedef unsigned int u32;
typedef u16 u16x8 __attribute__((ext_vector_type(8)));
typedef u16 u16x4 __attribute__((ext_vector_type(4)));
typedef __bf16 bf16x8 __attribute__((ext_vector_type(8)));
typedef float f32x4 __attribute__((ext_vector_type(4)));

#define B_ 64
#define T_ 256
#define D_ 256
#define H_ 1024
#define G4 4096
#define TC 64            // timesteps per chunk
#define MC 4096          // rows per chunk (B_*TC)
#define NCHUNK 4
#define NFLG 2048        // flags per chunk instance: [2 layer][8 wave][128 ublk]

// ---------- helpers ----------
__device__ __forceinline__ u16 f2bf(float x) {
  u32 u = __builtin_bit_cast(u32, x);
  u += 0x7fffu + ((u >> 16) & 1u);
  return (u16)(u >> 16);
}
__device__ __forceinline__ float bf2f(u16 h) {
  u32 u = ((u32)h) << 16;
  return __builtin_bit_cast(float, u);
}
__device__ __forceinline__ float sigmoidf_(float x) { return 1.f / (1.f + __expf(-x)); }

__device__ __forceinline__ f32x4 mfma16(u16x8 a, u16x8 b, f32x4 c) {
  return __builtin_amdgcn_mfma_f32_16x16x32_bf16(
      __builtin_bit_cast(bf16x8, a), __builtin_bit_cast(bf16x8, b), c, 0, 0, 0);
}

__device__ __forceinline__ void gl2lds16(const u16* g, u16* l) {
  __builtin_amdgcn_global_load_lds(
      (const __attribute__((address_space(1))) u32*)(const void*)g,
      (__attribute__((address_space(3))) u32*)(void*)l, 16, 0, 0);
}

// device-coherent (write-through past non-coherent L2) 4B store
__device__ __forceinline__ void store4_cc(u16* p, u32 v) {
  asm volatile("global_store_dword %0, %1, off sc0 sc1" :: "v"(p), "v"(v) : "memory");
}
__device__ __forceinline__ void store4_cc_u32(u32* p, u32 v) {
  asm volatile("global_store_dword %0, %1, off sc0 sc1" :: "v"(p), "v"(v) : "memory");
}
__device__ __forceinline__ void waitcnt0() {
  asm volatile("s_waitcnt vmcnt(0)" ::: "memory");
}

// ---------- split fp32 -> (hi, lo) bf16 planes ----------
__global__ void k_split(const float* __restrict__ src, u16* __restrict__ hi,
                        u16* __restrict__ lo, int n4) {
  int i = blockIdx.x * 256 + threadIdx.x;
  if (i >= n4) return;
  const float4* s4 = (const float4*)src;
  float4 v = s4[i];
  u16 h0 = f2bf(v.x), h1 = f2bf(v.y), h2 = f2bf(v.z), h3 = f2bf(v.w);
  u16x4 hv = {h0, h1, h2, h3};
  u16x4 lv = {f2bf(v.x - bf2f(h0)), f2bf(v.y - bf2f(h1)),
              f2bf(v.z - bf2f(h2)), f2bf(v.w - bf2f(h3))};
  *(u16x4*)(hi + 4 * (size_t)i) = hv;
  *(u16x4*)(lo + 4 * (size_t)i) = lv;
}

// gather one time-chunk of xx ([B,T,D] -> [B*TC, D]) and split planes
__global__ void k_split_x(const float* __restrict__ xx, u16* __restrict__ hi,
                          u16* __restrict__ lo, int t0) {
  int i = blockIdx.x * 256 + threadIdx.x;   // over MC * D_/4
  if (i >= MC * (D_ / 4)) return;
  int row = i >> 6, c4 = i & 63;
  int b = row >> 6, tc = row & 63;
  const float4* s4 = (const float4*)xx;
  float4 v = s4[(size_t)(b * T_ + t0 + tc) * (D_ / 4) + c4];
  u16 h0 = f2bf(v.x), h1 = f2bf(v.y), h2 = f2bf(v.z), h3 = f2bf(v.w);
  u16x4 hv = {h0, h1, h2, h3};
  u16x4 lv = {f2bf(v.x - bf2f(h0)), f2bf(v.y - bf2f(h1)),
              f2bf(v.z - bf2f(h2)), f2bf(v.w - bf2f(h3))};
  *(u16x4*)(hi + 4 * (size_t)i) = hv;
  *(u16x4*)(lo + 4 * (size_t)i) = lv;
}

__global__ void k_addvec(const float* __restrict__ a, const float* __restrict__ b,
                         float* __restrict__ o, int n) {
  int i = blockIdx.x * 256 + threadIdx.x;
  if (i < n) o[i] = a[i] + b[i];
}

// ---------- pack Wih1 (W21) into per-block MFMA-fragment order ----------
// frag idx = ((((blk*2+kh)*16+kc)*2+nt)*2+plane)*64 + lane ; each frag 16B.
__global__ void k_packw(const u16* __restrict__ hi, const u16* __restrict__ lo,
                        u16* __restrict__ wp) {
  int i = blockIdx.x * 256 + threadIdx.x;   // 1,048,576 frags
  int lane = i & 63;
  int pl = (i >> 6) & 1;
  int nt = (i >> 7) & 1;
  int kc = (i >> 8) & 15;
  int kh = (i >> 12) & 1;
  int blk = i >> 13;
  int n = nt * 16 + (lane & 15);
  int wrow = (n >> 3) * 1024 + blk * 8 + (n & 7);
  int k = kh * 512 + kc * 32 + (lane >> 4) * 8;
  const u16* src = (pl ? lo : hi) + (size_t)wrow * 1024 + k;
  *(u16x8*)(wp + (size_t)i * 8) = *(const u16x8*)src;
}

// ---------- split-precision GEMM: C[M,N] = A[M,K] * B[N,K]^T + bias (fp32 out) ----
// rec=0: standard C[m][n].
// rec=1: fused-kernel xg layout: idx = ((ublk*64 + t)*4 + gate)*512 + b*8 + uu
//   with unit=n&1023, ublk=unit>>3, uu=unit&7, gate=n>>10; A rows b-major
//   (b = m>>6, t = m&63).
__global__ __launch_bounds__(256, 2) void k_gemm3(
    const u16* __restrict__ Ah, const u16* __restrict__ Al,
    const u16* __restrict__ Bh, const u16* __restrict__ Bl,
    const float* __restrict__ bias, float* __restrict__ C,
    int M, int N, int K, int rec)
{
  __shared__ __attribute__((aligned(16))) u16 sAh[4096];
  __shared__ __attribute__((aligned(16))) u16 sAl[4096];
  __shared__ __attribute__((aligned(16))) u16 sBh[4096];
  __shared__ __attribute__((aligned(16))) u16 sBl[4096];

  const int tid = threadIdx.x;
  const int lane = tid & 63;
  const int wv = tid >> 6;
  const int wm = wv & 1, wn = wv >> 1;
  const int m0 = blockIdx.x * 128;
  const int n0 = blockIdx.y * 128;

  const int r0 = tid >> 2;
  const int kg = (tid & 3) ^ (r0 & 3);
  const size_t aoff0 = (size_t)(m0 + r0) * K + kg * 8;
  const size_t aoff1 = (size_t)(m0 + r0 + 64) * K + kg * 8;
  const size_t boff0 = (size_t)(n0 + r0) * K + kg * 8;
  const size_t boff1 = (size_t)(n0 + r0 + 64) * K + kg * 8;
  const int lb0 = wv * 512;
  const int lb1 = 2048 + wv * 512;

  const int l15 = lane & 15, l4 = lane >> 4;
  int afo[4], bfo[4];
#pragma unroll
  for (int mt = 0; mt < 4; ++mt) {
    int r = wm * 64 + mt * 16 + l15;
    afo[mt] = (r * 4 + (l4 ^ (r & 3))) * 8;
  }
#pragma unroll
  for (int nt = 0; nt < 4; ++nt) {
    int r = wn * 64 + nt * 16 + l15;
    bfo[nt] = (r * 4 + (l4 ^ (r & 3))) * 8;
  }

  f32x4 acc[4][4] = {};

  for (int k0 = 0; k0 < K; k0 += 32) {
    __syncthreads();
    gl2lds16(Ah + aoff0 + k0, &sAh[lb0]);
    gl2lds16(Ah + aoff1 + k0, &sAh[lb1]);
    gl2lds16(Al + aoff0 + k0, &sAl[lb0]);
    gl2lds16(Al + aoff1 + k0, &sAl[lb1]);
    gl2lds16(Bh + boff0 + k0, &sBh[lb0]);
    gl2lds16(Bh + boff1 + k0, &sBh[lb1]);
    gl2lds16(Bl + boff0 + k0, &sBl[lb0]);
    gl2lds16(Bl + boff1 + k0, &sBl[lb1]);
    __syncthreads();

    u16x8 a_h[4], a_l[4], b_h[4], b_l[4];
#pragma unroll
    for (int i = 0; i < 4; ++i) {
      a_h[i] = *(const u16x8*)&sAh[afo[i]];
      a_l[i] = *(const u16x8*)&sAl[afo[i]];
      b_h[i] = *(const u16x8*)&sBh[bfo[i]];
      b_l[i] = *(const u16x8*)&sBl[bfo[i]];
    }
#pragma unroll
    for (int mt = 0; mt < 4; ++mt)
#pragma unroll
      for (int nt = 0; nt < 4; ++nt) {
        acc[mt][nt] = mfma16(a_h[mt], b_h[nt], acc[mt][nt]);
        acc[mt][nt] = mfma16(a_l[mt], b_h[nt], acc[mt][nt]);
        acc[mt][nt] = mfma16(a_h[mt], b_l[nt], acc[mt][nt]);
      }
  }

  if (!rec) {
#pragma unroll
    for (int mt = 0; mt < 4; ++mt) {
      int mr = m0 + wm * 64 + mt * 16 + l4 * 4;
#pragma unroll
      for (int nt = 0; nt < 4; ++nt) {
        int nc = n0 + wn * 64 + nt * 16 + l15;
        float bv = bias[nc];
#pragma unroll
        for (int r = 0; r < 4; ++r)
          C[(size_t)(mr + r) * N + nc] = acc[mt][nt][r] + bv;
      }
    }
  } else {
#pragma unroll
    for (int mt = 0; mt < 4; ++mt) {
      int mr = m0 + wm * 64 + mt * 16 + l4 * 4;
#pragma unroll
      for (int nt = 0; nt < 4; ++nt) {
        int nc = n0 + wn * 64 + nt * 16 + l15;
        float bv = bias[nc];
        int unit = nc & 1023;
        int ublk = unit >> 3;
        int uu = unit & 7;
        int gate = nc >> 10;
#pragma unroll
        for (int r = 0; r < 4; ++r) {
          int m = mr + r;
          size_t idx = ((size_t)(ublk * 64 + (m & 63)) * 4 + gate) * 512 + (m >> 6) * 8 + uu;
          C[idx] = acc[mt][nt][r] + bv;
        }
      }
    }
  }
}

// ---------- l1 pointwise on one chunk ----------
__global__ void k_pw(const float* __restrict__ xg, u16* __restrict__ hhi,
                     u16* __restrict__ hlo) {
  int idx = blockIdx.x * 256 + threadIdx.x;  // MC*H_ threads
  int r = idx >> 10, j = idx & 1023;
  const float* g = xg + (size_t)r * G4;
  float cc = sigmoidf_(g[j]) * tanhf(g[2048 + j]);
  float h = sigmoidf_(g[3072 + j]) * tanhf(cc);
  u16 hh = f2bf(h);
  hhi[idx] = hh;
  hlo[idx] = f2bf(h - bf2f(hh));
}

// ---------- fused persistent recurrent LSTM (BOTH l2 layers), one chunk ----------
// 256 blocks x 512 threads, 1 block/CU (149.5KB LDS).
//   blk>>7 = layer L (0/1), blk&127 = ublk (8 units, 32 gate-cols, Whh slice in LDS).
// Layer-1 lags layer-0 by one round: round r computes h0[r] (L=0 blocks, rounds
// 0..63) and h1[r-1] (L=1 blocks, rounds 1..64). Layer-1 computes its own input
// gates on the fly: gates = Wih1@h0[r-1] + Whh1@h1[r-2] + bias, with Wih1 streamed
// from L2 in pre-packed fragment order (k_packw).
// Sync: per-producer-wave dense flags [L][wave][ublk]; uniform protocol:
// poll >= r, raise r+1 after own-wave sc0sc1 drain. Layer-0 polls only layer-0
// flags (closed set -> progress); layer-1 polls layer-0 (past) + own past rounds.
__global__ __launch_bounds__(512, 2) void k_fused(
    const float* __restrict__ xg,                      // layer0 gates (64 MB)
    const u16* __restrict__ W0hi, const u16* __restrict__ W0lo,  // Whh0 [4096][1024]
    const u16* __restrict__ W1hi, const u16* __restrict__ W1lo,  // Whh1
    const u16* __restrict__ WP,                        // packed Wih1 frags (16 MB)
    const float* __restrict__ bs3,                     // layer1 bias (bih+bhh)
    u16* __restrict__ r0H, u16* __restrict__ r0L,      // h0 ring [64][64][1024]
    u16* __restrict__ r1H, u16* __restrict__ r1L,      // h1 ring
    u16* __restrict__ h00H, u16* __restrict__ h00L,    // h0 chunk carry [64][1024]
    u16* __restrict__ h01H, u16* __restrict__ h01L,    // h1 chunk carry
    float* __restrict__ cb0, float* __restrict__ cb1,  // c state [64][1024]
    float* __restrict__ hfinal,                        // [64][1024] or null
    u32* __restrict__ flags)                           // NFLG dense flags
{
  __shared__ __attribute__((aligned(16))) u16 sW[66048];  // [2][32][1032]  129 KB
  __shared__ float sg[2][64][34];                          // [kh][m][col]   17 KB
  __shared__ int sDead;

  const int tid = threadIdx.x;
  const int lane = tid & 63, wv = tid >> 6;
  const int l15 = lane & 15, l4 = lane >> 4;
  const int blk = blockIdx.x;
  const int L = blk >> 7, ublk = blk & 127;
  const int u0 = ublk * 8;

  const u16* Whi = L ? W1hi : W0hi;
  const u16* Wlo = L ? W1lo : W0lo;
  u16* ringOH = L ? r1H : r0H;
  u16* ringOL = L ? r1L : r0L;
  u16* carryH = L ? h01H : h00H;
  u16* carryL = L ? h01L : h00L;
  float* cbp = L ? cb1 : cb0;

  if (tid == 0) sDead = 0;

  // ---- one-time: Whh slice (32 gate-cols x 1024, hi+lo) into LDS ----
  for (int ci = tid; ci < 8192; ci += 512) {
    int plane = ci >> 12, rem = ci & 4095;
    int n = rem >> 7, ch = rem & 127;
    int wrow = (n >> 3) * 1024 + u0 + (n & 7);
    const u16* src = (plane ? Wlo : Whi) + (size_t)wrow * 1024 + ch * 8;
    *(u16x8*)&sW[plane * 33024 + n * 1032 + ch * 8] = *(const u16x8*)src;
  }
  __syncthreads();

  const int mt = wv >> 1, kh = wv & 1;        // m-tile (16 batches), k-half (512)
  const int aoff = (mt * 16 + l15) * 1024 + kh * 512 + l4 * 8;
  const int bof0 = l15 * 1032 + kh * 512 + l4 * 8;
  const int bof1 = (16 + l15) * 1032 + kh * 512 + l4 * 8;
  const size_t wpb = (size_t)(ublk * 2 + kh) * 32768 + lane * 8;  // packed Wih base

  // flag regions (ring0 producers: rows 0..7; ring1: rows 8..15)
  const u32* f0a = flags + (2 * mt) * 128 + kh * 64 + lane;
  const u32* f0b = flags + (2 * mt + 1) * 128 + kh * 64 + lane;
  const u32* f1a = flags + (8 + 2 * mt) * 128 + kh * 64 + lane;
  const u32* f1b = flags + (8 + 2 * mt + 1) * 128 + kh * 64 + lane;
  u32* fown = flags + (L * 8 + wv) * 128 + ublk;

  // pointwise cell: batch pb (0..63), unit uu (0..7)
  const int pb = tid >> 3, uu = tid & 7;
  const int cidx = pb * 1024 + u0 + uu;
  float c = cbp[cidx];
  float bv0 = 0.f, bv1 = 0.f, bv2 = 0.f, bv3 = 0.f;
  if (L) {
    bv0 = bs3[u0 + uu];
    bv1 = bs3[1024 + u0 + uu];
    bv2 = bs3[2048 + u0 + uu];
    bv3 = bs3[3072 + u0 + uu];
  }
  const float* xgb = xg + (size_t)ublk * 131072 + pb * 8 + uu;

  const int rBeg = L, rEnd = 63 + L;
  for (int r = rBeg; r <= rEnd; ++r) {
    const int t = r - L;

    // ---- xg prefetch (layer 0 only; produced by earlier dispatch) ----
    float px0, px1, px2, px3;
    if (!L) {
      const float* xa = xgb + (size_t)t * 2048;
      asm volatile("global_load_dword %0, %1, off" : "=v"(px0) : "v"(xa));
      asm volatile("global_load_dword %0, %1, off" : "=v"(px1) : "v"(xa + 512));
      asm volatile("global_load_dword %0, %1, off" : "=v"(px2) : "v"(xa + 1024));
      asm volatile("global_load_dword %0, %1, off" : "=v"(px3) : "v"(xa + 1536));
    }

    // ---- per-wave poll (uniform: need >= r) ----
    if (*(volatile int*)&sDead == 0) {
      const u32 need = (u32)r;
      if (!L) {
        if (r > 0) {
          int guard = 0;
          for (;;) {
            u32 a = __hip_atomic_load(f0a, __ATOMIC_RELAXED, __HIP_MEMORY_SCOPE_AGENT);
            u32 b = __hip_atomic_load(f0b, __ATOMIC_RELAXED, __HIP_MEMORY_SCOPE_AGENT);
            if (a >= need && b >= need) break;
            if (++guard > (1 << 17)) { if (lane == 0) sDead = 1; break; }
            __builtin_amdgcn_s_sleep(1);
          }
        }
      } else {
        const bool own2 = (r > 1);
        int guard = 0;
        for (;;) {
          u32 a = __hip_atomic_load(f0a, __ATOMIC_RELAXED, __HIP_MEMORY_SCOPE_AGENT);
          u32 b = __hip_atomic_load(f0b, __ATOMIC_RELAXED, __HIP_MEMORY_SCOPE_AGENT);
          u32 c2 = own2 ? __hip_atomic_load(f1a, __ATOMIC_RELAXED, __HIP_MEMORY_SCOPE_AGENT) : need;
          u32 d2 = own2 ? __hip_atomic_load(f1b, __ATOMIC_RELAXED, __HIP_MEMORY_SCOPE_AGENT) : need;
          if (a >= need && b >= need && c2 >= need && d2 >= need) break;
          if (++guard > (1 << 17)) { if (lane == 0) sDead = 1; break; }
          __builtin_amdgcn_s_sleep(1);
        }
      }
    }

    // ---- A-operand pointers ----
    const u16 *oah, *oal;                 // own-state h_L[t-1]
    if (r > rBeg) {
      oah = ringOH + (size_t)(t - 1) * 65536 + aoff;
      oal = ringOL + (size_t)(t - 1) * 65536 + aoff;
    } else {
      oah = carryH + aoff;
      oal = carryL + aoff;
    }
    const u16 *xah = nullptr, *xal = nullptr;   // cross h0[r-1] (layer 1)
    if (L) {
      xah = r0H + (size_t)(r - 1) * 65536 + aoff;
      xal = r0L + (size_t)(r - 1) * 65536 + aoff;
    }

    // ---- matmul over this wave's k-half ----
    f32x4 aq[2][2] = {};   // [nt][kc parity]
#pragma unroll
    for (int kc = 0; kc < 16; ++kc) {
      const int ko = kc * 32;
      u16x8 oh = *(const u16x8*)(oah + ko);
      u16x8 ol = *(const u16x8*)(oal + ko);
      u16x8 b0h = *(const u16x8*)&sW[bof0 + ko];
      u16x8 b0l = *(const u16x8*)&sW[33024 + bof0 + ko];
      u16x8 b1h = *(const u16x8*)&sW[bof1 + ko];
      u16x8 b1l = *(const u16x8*)&sW[33024 + bof1 + ko];
      if (!L) {
        aq[0][kc & 1] = mfma16(oh, b0h, aq[0][kc & 1]);
        aq[0][kc & 1] = mfma16(ol, b0h, aq[0][kc & 1]);
        aq[0][kc & 1] = mfma16(oh, b0l, aq[0][kc & 1]);
        aq[1][kc & 1] = mfma16(oh, b1h, aq[1][kc & 1]);
        aq[1][kc & 1] = mfma16(ol, b1h, aq[1][kc & 1]);
        aq[1][kc & 1] = mfma16(oh, b1l, aq[1][kc & 1]);
      } else {
        u16x8 ch_ = *(const u16x8*)(xah + ko);
        u16x8 cl_ = *(const u16x8*)(xal + ko);
        const u16* wq = WP + wpb + kc * 2048;
        u16x8 w0h = *(const u16x8*)(wq);
        u16x8 w0l = *(const u16x8*)(wq + 512);
        u16x8 w1h = *(const u16x8*)(wq + 1024);
        u16x8 w1l = *(const u16x8*)(wq + 1536);
        aq[0][kc & 1] = mfma16(oh, b0h, aq[0][kc & 1]);
        aq[0][kc & 1] = mfma16(ol, b0h, aq[0][kc & 1]);
        aq[0][kc & 1] = mfma16(oh, b0l, aq[0][kc & 1]);
        aq[0][kc & 1] = mfma16(ch_, w0h, aq[0][kc & 1]);
        aq[0][kc & 1] = mfma16(cl_, w0h, aq[0][kc & 1]);
        aq[0][kc & 1] = mfma16(ch_, w0l, aq[0][kc & 1]);
        aq[1][kc & 1] = mfma16(oh, b1h, aq[1][kc & 1]);
        aq[1][kc & 1] = mfma16(ol, b1h, aq[1][kc & 1]);
        aq[1][kc & 1] = mfma16(oh, b1l, aq[1][kc & 1]);
        aq[1][kc & 1] = mfma16(ch_, w1h, aq[1][kc & 1]);
        aq[1][kc & 1] = mfma16(cl_, w1h, aq[1][kc & 1]);
        aq[1][kc & 1] = mfma16(ch_, w1l, aq[1][kc & 1]);
      }
    }
    f32x4 A0 = aq[0][0] + aq[0][1];
    f32x4 A1 = aq[1][0] + aq[1][1];

    __syncthreads();   // prev round's sg fully consumed
#pragma unroll
    for (int r4 = 0; r4 < 4; ++r4) {
      int m = mt * 16 + l4 * 4 + r4;
      sg[kh][m][l15] = A0[r4];
      sg[kh][m][16 + l15] = A1[r4];
    }
    __syncthreads();   // sg ready

    // ---- pointwise on all 512 threads ----
    float g0 = sg[0][pb][uu] + sg[1][pb][uu];
    float g1 = sg[0][pb][8 + uu] + sg[1][pb][8 + uu];
    float g2 = sg[0][pb][16 + uu] + sg[1][pb][16 + uu];
    float g3 = sg[0][pb][24 + uu] + sg[1][pb][24 + uu];
    if (!L) {
      waitcnt0();  // px ready
      g0 += px0; g1 += px1; g2 += px2; g3 += px3;
    } else {
      g0 += bv0; g1 += bv1; g2 += bv2; g3 += bv3;
    }
    c = sigmoidf_(g1) * c + sigmoidf_(g0) * tanhf(g2);
    float h = sigmoidf_(g3) * tanhf(c);
    u32 hiu = (u32)f2bf(h);
    u32 lou = (u32)f2bf(h - bf2f((u16)hiu));
    u32 hiN = __shfl_down(hiu, 1);
    u32 loN = __shfl_down(lou, 1);
    if ((tid & 1) == 0) {
      size_t re = (size_t)t * 65536 + (size_t)pb * 1024 + u0 + uu;
      store4_cc(ringOH + re, hiu | (hiN << 16));
      store4_cc(ringOL + re, lou | (loN << 16));
      if (t == 63) {
        store4_cc(carryH + cidx, hiu | (hiN << 16));
        store4_cc(carryL + cidx, lou | (loN << 16));
      }
    }
    if (hfinal && L && t == 63) hfinal[cidx] = h;

    // ---- drain own wave's stores, raise own flag ----
    waitcnt0();
    if (lane == 0) store4_cc_u32(fown, (u32)(r + 1));
  }

  cbp[cidx] = c;
}

// ---------- MLP (fp32 vector) ----------
__global__ void k_fc(const float* __restrict__ in, const float* __restrict__ W,
                     const float* __restrict__ bias, float* __restrict__ out,
                     int K, int N, int relu) {
  int b = blockIdx.x;
  int n = blockIdx.y * 256 + threadIdx.x;
  if (n >= N) return;
  const float4* wr = (const float4*)(W + (size_t)n * K);
  const float4* xr = (const float4*)(in + (size_t)b * K);
  float s = 0.f;
  for (int k = 0; k < K / 4; ++k) {
    float4 w = wr[k], x = xr[k];
    s += w.x * x.x + w.y * x.y + w.z * x.z + w.w * x.w;
  }
  s += bias[n];
  if (relu) s = fmaxf(s, 0.f);
  out[(size_t)b * N + n] = s;
}

__global__ void k_out(const float* __restrict__ z, const float* __restrict__ W3,
                      const float* __restrict__ b3, float* __restrict__ outp) {
  int b = blockIdx.x;
  int lane = threadIdx.x;  // 64
  const float4* wr = (const float4*)W3;
  const float4* xr = (const float4*)(z + b * 512);
  float s = 0.f;
  for (int k = lane; k < 128; k += 64) {
    float4 w = wr[k], x = xr[k];
    s += w.x * x.x + w.y * x.y + w.z * x.z + w.w * x.w;
  }
  for (int off = 32; off; off >>= 1) s += __shfl_down(s, off);
  if (lane == 0) outp[b] = s + b3[0];
}

// ---------- launch ----------
extern "C" void kernel_launch(void* const* d_in, const int* in_sizes, int n_in,
                              void* d_out, int out_size, void* d_ws, size_t ws_size,
                              hipStream_t stream) {
  (void)in_sizes; (void)n_in; (void)out_size; (void)ws_size;
  const float* xx  = (const float*)d_in[0];
  const float* W10 = (const float*)d_in[1];
  const float* b10i = (const float*)d_in[2];
  const float* b10h = (const float*)d_in[3];
  const float* W11 = (const float*)d_in[4];
  const float* b11i = (const float*)d_in[5];
  const float* b11h = (const float*)d_in[6];
  const float* W20 = (const float*)d_in[7];
  const float* Wh0 = (const float*)d_in[8];
  const float* b20i = (const float*)d_in[9];
  const float* b20h = (const float*)d_in[10];
  const float* W21 = (const float*)d_in[11];
  const float* Wh1 = (const float*)d_in[12];
  const float* b21i = (const float*)d_in[13];
  const float* b21h = (const float*)d_in[14];
  const float* mW1 = (const float*)d_in[15];
  const float* mb1 = (const float*)d_in[16];
  const float* mW2 = (const float*)d_in[17];
  const float* mb2 = (const float*)d_in[18];
  const float* mW3 = (const float*)d_in[19];
  const float* mb3 = (const float*)d_in[20];

  char* ws = (char*)d_ws;
  size_t o = 0;
  float* XG = (float*)(ws + o); o += (size_t)MC * G4 * 4;            // 64 MiB
  u16* Aah = (u16*)(ws + o); o += (size_t)MC * H_ * 2;               // l1 ping / h1 ring
  u16* Aal = (u16*)(ws + o); o += (size_t)MC * H_ * 2;
  u16* Abh = (u16*)(ws + o); o += (size_t)MC * H_ * 2;               // l1 pong / h0 ring
  u16* Abl = (u16*)(ws + o); o += (size_t)MC * H_ * 2;
  u16* XXh = (u16*)(ws + o); o += (size_t)MC * D_ * 2;
  u16* XXl = (u16*)(ws + o); o += (size_t)MC * D_ * 2;
  u16* W10h = (u16*)(ws + o); o += (size_t)G4 * D_ * 2;
  u16* W10l = (u16*)(ws + o); o += (size_t)G4 * D_ * 2;
  u16* W11h = (u16*)(ws + o); o += (size_t)G4 * H_ * 2;
  u16* W11l = (u16*)(ws + o); o += (size_t)G4 * H_ * 2;
  u16* W20h = (u16*)(ws + o); o += (size_t)G4 * H_ * 2;
  u16* W20l = (u16*)(ws + o); o += (size_t)G4 * H_ * 2;
  u16* Wh0h = (u16*)(ws + o); o += (size_t)G4 * H_ * 2;
  u16* Wh0l = (u16*)(ws + o); o += (size_t)G4 * H_ * 2;
  u16* W21h = (u16*)(ws + o); o += (size_t)G4 * H_ * 2;
  u16* W21l = (u16*)(ws + o); o += (size_t)G4 * H_ * 2;
  u16* Wh1h = (u16*)(ws + o); o += (size_t)G4 * H_ * 2;
  u16* Wh1l = (u16*)(ws + o); o += (size_t)G4 * H_ * 2;
  u16* WP21 = (u16*)(ws + o); o += (size_t)1048576 * 16;             // 16 MiB packed Wih1
  float* bs0 = (float*)(ws + o); o += G4 * 4;
  float* bs1 = (float*)(ws + o); o += G4 * 4;
  float* bs2 = (float*)(ws + o); o += G4 * 4;
  float* bs3 = (float*)(ws + o); o += G4 * 4;
  // state region (zeroed once per launch, contiguous)
  char* ST = ws + o;
  u16* h00H = (u16*)(ws + o); o += B_ * H_ * 2;
  u16* h00L = (u16*)(ws + o); o += B_ * H_ * 2;
  u16* h01H = (u16*)(ws + o); o += B_ * H_ * 2;
  u16* h01L = (u16*)(ws + o); o += B_ * H_ * 2;
  float* cb0 = (float*)(ws + o); o += B_ * H_ * 4;
  float* cb1 = (float*)(ws + o); o += B_ * H_ * 4;
  u32* FLG = (u32*)(ws + o); o += NCHUNK * NFLG * 4;   // 4 instances x 2048 flags
  size_t stBytes = (size_t)((ws + o) - ST);
  float* FH = (float*)(ws + o); o += B_ * H_ * 4;
  float* Z1 = (float*)(ws + o); o += B_ * H_ * 4;
  float* Z2 = (float*)(ws + o); o += B_ * 512 * 4;

  // --- one-time weight/bias prep ---
  k_split<<<(G4 * D_ / 4 + 255) / 256, 256, 0, stream>>>(W10, W10h, W10l, G4 * D_ / 4);
  k_split<<<(G4 * H_ / 4 + 255) / 256, 256, 0, stream>>>(W11, W11h, W11l, G4 * H_ / 4);
  k_split<<<(G4 * H_ / 4 + 255) / 256, 256, 0, stream>>>(W20, W20h, W20l, G4 * H_ / 4);
  k_split<<<(G4 * H_ / 4 + 255) / 256, 256, 0, stream>>>(Wh0, Wh0h, Wh0l, G4 * H_ / 4);
  k_split<<<(G4 * H_ / 4 + 255) / 256, 256, 0, stream>>>(W21, W21h, W21l, G4 * H_ / 4);
  k_split<<<(G4 * H_ / 4 + 255) / 256, 256, 0, stream>>>(Wh1, Wh1h, Wh1l, G4 * H_ / 4);
  k_packw<<<4096, 256, 0, stream>>>(W21h, W21l, WP21);
  k_addvec<<<16, 256, 0, stream>>>(b10i, b10h, bs0, G4);
  k_addvec<<<16, 256, 0, stream>>>(b11i, b11h, bs1, G4);
  k_addvec<<<16, 256, 0, stream>>>(b20i, b20h, bs2, G4);
  k_addvec<<<16, 256, 0, stream>>>(b21i, b21h, bs3, G4);
  hipMemsetAsync(ST, 0, stBytes, stream);

  dim3 gg(MC / 128, G4 / 128);
  const int pwBlocks = MC * H_ / 256;

  for (int c = 0; c < NCHUNK; ++c) {
    int t0 = c * TC;
    k_split_x<<<(MC * (D_ / 4) + 255) / 256, 256, 0, stream>>>(xx, XXh, XXl, t0);
    // l1 layer 0
    k_gemm3<<<gg, 256, 0, stream>>>(XXh, XXl, W10h, W10l, bs0, XG, MC, G4, D_, 0);
    k_pw<<<pwBlocks, 256, 0, stream>>>(XG, Aah, Aal);
    // l1 layer 1
    k_gemm3<<<gg, 256, 0, stream>>>(Aah, Aal, W11h, W11l, bs1, XG, MC, G4, H_, 0);
    k_pw<<<pwBlocks, 256, 0, stream>>>(XG, Abh, Abl);
    // l2 layer 0 gates (fused layout), then fused dual-layer recurrence
    k_gemm3<<<gg, 256, 0, stream>>>(Abh, Abl, W20h, W20l, bs2, XG, MC, G4, H_, 1);
    k_fused<<<256, 512, 0, stream>>>(XG, Wh0h, Wh0l, Wh1h, Wh1l, WP21, bs3,
                                     Abh, Abl, Aah, Aal,
                                     h00H, h00L, h01H, h01L, cb0, cb1,
                                     (c == NCHUNK - 1) ? FH : nullptr,
                                     FLG + c * NFLG);
  }

  // MLP
  k_fc<<<dim3(B_, 4), 256, 0, stream>>>(FH, mW1, mb1, Z1, H_, H_, 1);
  k_fc<<<dim3(B_, 2), 256, 0, stream>>>(Z1, mW2, mb2, Z2, H_, 512, 1);
  k_out<<<B_, 64, 0, stream>>>(Z2, mW3, mb3, (float*)d_out);
}

// Round 3
// 4833.400 us; speedup vs baseline: 1.3773x; 1.3773x over previous
//
#include <hip/hip_runtime.h>

typedef unsigned short u16;
typedef unsigned int u32;
typedef u16 u16x8 __attribute__((ext_vector_type(8)));
typedef u16 u16x4 __attribute__((ext_vector_type(4)));
typedef __bf16 bf16x8 __attribute__((ext_vector_type(8)));
typedef float f32x4 __attribute__((ext_vector_type(4)));

#define B_ 64
#define T_ 256
#define D_ 256
#define H_ 1024
#define G4 4096
#define TC 64            // timesteps per chunk
#define MC 4096          // rows per chunk (B_*TC)
#define NCHUNK 4
#define NFLG 2048        // flags per dispatch: [2 half][8 wave][128 ublk]

// ---------- helpers ----------
__device__ __forceinline__ u16 f2bf(float x) {
  u32 u = __builtin_bit_cast(u32, x);
  u += 0x7fffu + ((u >> 16) & 1u);
  return (u16)(u >> 16);
}
__device__ __forceinline__ float bf2f(u16 h) {
  u32 u = ((u32)h) << 16;
  return __builtin_bit_cast(float, u);
}
__device__ __forceinline__ float sigmoidf_(float x) { return 1.f / (1.f + __expf(-x)); }

__device__ __forceinline__ f32x4 mfma16(u16x8 a, u16x8 b, f32x4 c) {
  return __builtin_amdgcn_mfma_f32_16x16x32_bf16(
      __builtin_bit_cast(bf16x8, a), __builtin_bit_cast(bf16x8, b), c, 0, 0, 0);
}

__device__ __forceinline__ void gl2lds16(const u16* g, u16* l) {
  __builtin_amdgcn_global_load_lds(
      (const __attribute__((address_space(1))) u32*)(const void*)g,
      (__attribute__((address_space(3))) u32*)(void*)l, 16, 0, 0);
}

// device-coherent (write-through past non-coherent L2) 4B store
__device__ __forceinline__ void store4_cc(u16* p, u32 v) {
  asm volatile("global_store_dword %0, %1, off sc0 sc1" :: "v"(p), "v"(v) : "memory");
}
__device__ __forceinline__ void store4_cc_u32(u32* p, u32 v) {
  asm volatile("global_store_dword %0, %1, off sc0 sc1" :: "v"(p), "v"(v) : "memory");
}
__device__ __forceinline__ void waitcnt0() {
  asm volatile("s_waitcnt vmcnt(0)" ::: "memory");
}

// ---------- split fp32 -> (hi, lo) bf16 planes ----------
__global__ void k_split(const float* __restrict__ src, u16* __restrict__ hi,
                        u16* __restrict__ lo, int n4) {
  int i = blockIdx.x * 256 + threadIdx.x;
  if (i >= n4) return;
  const float4* s4 = (const float4*)src;
  float4 v = s4[i];
  u16 h0 = f2bf(v.x), h1 = f2bf(v.y), h2 = f2bf(v.z), h3 = f2bf(v.w);
  u16x4 hv = {h0, h1, h2, h3};
  u16x4 lv = {f2bf(v.x - bf2f(h0)), f2bf(v.y - bf2f(h1)),
              f2bf(v.z - bf2f(h2)), f2bf(v.w - bf2f(h3))};
  *(u16x4*)(hi + 4 * (size_t)i) = hv;
  *(u16x4*)(lo + 4 * (size_t)i) = lv;
}

// gather one time-chunk of xx ([B,T,D] -> [B*TC, D]) and split planes
__global__ void k_split_x(const float* __restrict__ xx, u16* __restrict__ hi,
                          u16* __restrict__ lo, int t0) {
  int i = blockIdx.x * 256 + threadIdx.x;   // over MC * D_/4
  if (i >= MC * (D_ / 4)) return;
  int row = i >> 6, c4 = i & 63;
  int b = row >> 6, tc = row & 63;
  const float4* s4 = (const float4*)xx;
  float4 v = s4[(size_t)(b * T_ + t0 + tc) * (D_ / 4) + c4];
  u16 h0 = f2bf(v.x), h1 = f2bf(v.y), h2 = f2bf(v.z), h3 = f2bf(v.w);
  u16x4 hv = {h0, h1, h2, h3};
  u16x4 lv = {f2bf(v.x - bf2f(h0)), f2bf(v.y - bf2f(h1)),
              f2bf(v.z - bf2f(h2)), f2bf(v.w - bf2f(h3))};
  *(u16x4*)(hi + 4 * (size_t)i) = hv;
  *(u16x4*)(lo + 4 * (size_t)i) = lv;
}

__global__ void k_addvec(const float* __restrict__ a, const float* __restrict__ b,
                         float* __restrict__ o, int n) {
  int i = blockIdx.x * 256 + threadIdx.x;
  if (i < n) o[i] = a[i] + b[i];
}

// ---------- split-precision GEMM: C[M,N] = A[M,K] * B[N,K]^T + bias (fp32 out) ----
// rec=0: standard C[m][n].
// rec=1/2: recurrent xg layout: idx = ((ublk*64 + t)*4 + gate)*512 + b*8 + uu
//   with unit=n&1023, ublk=unit>>3, uu=unit&7, gate=n>>10.
//   rec=1: A rows b-major (b=m>>6, t=m&63)  [l1 output]
//   rec=2: A rows t-major (t=m>>6, b=m&63)  [h ring]
__global__ __launch_bounds__(256, 2) void k_gemm3(
    const u16* __restrict__ Ah, const u16* __restrict__ Al,
    const u16* __restrict__ Bh, const u16* __restrict__ Bl,
    const float* __restrict__ bias, float* __restrict__ C,
    int M, int N, int K, int rec)
{
  __shared__ __attribute__((aligned(16))) u16 sAh[4096];
  __shared__ __attribute__((aligned(16))) u16 sAl[4096];
  __shared__ __attribute__((aligned(16))) u16 sBh[4096];
  __shared__ __attribute__((aligned(16))) u16 sBl[4096];

  const int tid = threadIdx.x;
  const int lane = tid & 63;
  const int wv = tid >> 6;
  const int wm = wv & 1, wn = wv >> 1;
  const int m0 = blockIdx.x * 128;
  const int n0 = blockIdx.y * 128;

  const int r0 = tid >> 2;
  const int kg = (tid & 3) ^ (r0 & 3);
  const size_t aoff0 = (size_t)(m0 + r0) * K + kg * 8;
  const size_t aoff1 = (size_t)(m0 + r0 + 64) * K + kg * 8;
  const size_t boff0 = (size_t)(n0 + r0) * K + kg * 8;
  const size_t boff1 = (size_t)(n0 + r0 + 64) * K + kg * 8;
  const int lb0 = wv * 512;
  const int lb1 = 2048 + wv * 512;

  const int l15 = lane & 15, l4 = lane >> 4;
  int afo[4], bfo[4];
#pragma unroll
  for (int mt = 0; mt < 4; ++mt) {
    int r = wm * 64 + mt * 16 + l15;
    afo[mt] = (r * 4 + (l4 ^ (r & 3))) * 8;
  }
#pragma unroll
  for (int nt = 0; nt < 4; ++nt) {
    int r = wn * 64 + nt * 16 + l15;
    bfo[nt] = (r * 4 + (l4 ^ (r & 3))) * 8;
  }

  f32x4 acc[4][4] = {};

  for (int k0 = 0; k0 < K; k0 += 32) {
    __syncthreads();
    gl2lds16(Ah + aoff0 + k0, &sAh[lb0]);
    gl2lds16(Ah + aoff1 + k0, &sAh[lb1]);
    gl2lds16(Al + aoff0 + k0, &sAl[lb0]);
    gl2lds16(Al + aoff1 + k0, &sAl[lb1]);
    gl2lds16(Bh + boff0 + k0, &sBh[lb0]);
    gl2lds16(Bh + boff1 + k0, &sBh[lb1]);
    gl2lds16(Bl + boff0 + k0, &sBl[lb0]);
    gl2lds16(Bl + boff1 + k0, &sBl[lb1]);
    __syncthreads();

    u16x8 a_h[4], a_l[4], b_h[4], b_l[4];
#pragma unroll
    for (int i = 0; i < 4; ++i) {
      a_h[i] = *(const u16x8*)&sAh[afo[i]];
      a_l[i] = *(const u16x8*)&sAl[afo[i]];
      b_h[i] = *(const u16x8*)&sBh[bfo[i]];
      b_l[i] = *(const u16x8*)&sBl[bfo[i]];
    }
#pragma unroll
    for (int mt = 0; mt < 4; ++mt)
#pragma unroll
      for (int nt = 0; nt < 4; ++nt) {
        acc[mt][nt] = mfma16(a_h[mt], b_h[nt], acc[mt][nt]);
        acc[mt][nt] = mfma16(a_l[mt], b_h[nt], acc[mt][nt]);
        acc[mt][nt] = mfma16(a_h[mt], b_l[nt], acc[mt][nt]);
      }
  }

  if (!rec) {
#pragma unroll
    for (int mt = 0; mt < 4; ++mt) {
      int mr = m0 + wm * 64 + mt * 16 + l4 * 4;
#pragma unroll
      for (int nt = 0; nt < 4; ++nt) {
        int nc = n0 + wn * 64 + nt * 16 + l15;
        float bv = bias[nc];
#pragma unroll
        for (int r = 0; r < 4; ++r)
          C[(size_t)(mr + r) * N + nc] = acc[mt][nt][r] + bv;
      }
    }
  } else {
#pragma unroll
    for (int mt = 0; mt < 4; ++mt) {
      int mr = m0 + wm * 64 + mt * 16 + l4 * 4;
#pragma unroll
      for (int nt = 0; nt < 4; ++nt) {
        int nc = n0 + wn * 64 + nt * 16 + l15;
        float bv = bias[nc];
        int unit = nc & 1023;
        int ublk = unit >> 3;
        int uu = unit & 7;
        int gate = nc >> 10;
#pragma unroll
        for (int r = 0; r < 4; ++r) {
          int m = mr + r;
          int tq = (rec == 1) ? (m & 63) : (m >> 6);
          int bq = (rec == 1) ? (m >> 6) : (m & 63);
          size_t idx = ((size_t)(ublk * 64 + tq) * 4 + gate) * 512 + bq * 8 + uu;
          C[idx] = acc[mt][nt][r] + bv;
        }
      }
    }
  }
}

// ---------- l1 pointwise on one chunk ----------
__global__ void k_pw(const float* __restrict__ xg, u16* __restrict__ hhi,
                     u16* __restrict__ hlo) {
  int idx = blockIdx.x * 256 + threadIdx.x;  // MC*H_ threads
  int r = idx >> 10, j = idx & 1023;
  const float* g = xg + (size_t)r * G4;
  float cc = sigmoidf_(g[j]) * tanhf(g[2048 + j]);
  float h = sigmoidf_(g[3072 + j]) * tanhf(cc);
  u16 hh = f2bf(h);
  hhi[idx] = hh;
  hlo[idx] = f2bf(h - bf2f(hh));
}

// ---------- dual-instance persistent recurrent LSTM dispatch ----------
// 256 blocks x 512 threads, 1 block/CU (146.5KB LDS).
//   blk>>7 = half (A: rec-layer0 chunk c; B: rec-layer1 chunk c-1), blk&127 = ublk.
// The two halves are INDEPENDENT recurrences (B's input gates were computed by a
// dense GEMM from half-A's previous-chunk h0 ring). Each half runs the proven v2
// protocol: sc0sc1 ring stores, per-producer-wave dense flags [half][wave][ublk],
// own-wave vmcnt drain before flag raise, relaxed agent polls; a half with a null
// xg pointer idles (first dispatch has no B work, last has no A work).
__global__ __launch_bounds__(512, 2) void k_recd(
    const float* __restrict__ xgA, const float* __restrict__ xgB,
    const u16* __restrict__ WAhi, const u16* __restrict__ WAlo,
    const u16* __restrict__ WBhi, const u16* __restrict__ WBlo,
    u16* __restrict__ rAH, u16* __restrict__ rAL,   // half-A h ring [64][64][1024]
    u16* __restrict__ rBH, u16* __restrict__ rBL,   // half-B h ring
    u16* __restrict__ cAH, u16* __restrict__ cAL,   // chunk-carry h [64][1024]
    u16* __restrict__ cBH, u16* __restrict__ cBL,
    float* __restrict__ cbA, float* __restrict__ cbB,  // c state [64][1024]
    float* __restrict__ hfB,                        // [64][1024] or null (half B)
    u32* __restrict__ flags)                        // NFLG dense flags
{
  __shared__ __attribute__((aligned(16))) u16 sW[66048];  // [2][32][1032]  129 KB
  __shared__ float sg[2][64][34];                          // [kh][m][col]   17 KB
  __shared__ int sDead;

  const int tid = threadIdx.x;
  const int lane = tid & 63, wv = tid >> 6;
  const int l15 = lane & 15, l4 = lane >> 4;
  const int L = blockIdx.x >> 7, ublk = blockIdx.x & 127;
  const int u0 = ublk * 8;

  const float* xg = L ? xgB : xgA;
  if (!xg) return;
  const u16* Whi = L ? WBhi : WAhi;
  const u16* Wlo = L ? WBlo : WAlo;
  u16* ringH = L ? rBH : rAH;
  u16* ringL = L ? rBL : rAL;
  u16* carryH = L ? cBH : cAH;
  u16* carryL = L ? cBL : cAL;
  float* cbp = L ? cbB : cbA;
  float* hfinal = L ? hfB : nullptr;
  u32* flg = flags + L * 1024;

  if (tid == 0) sDead = 0;

  // ---- one-time: Whh slice (32 gate-cols x 1024, hi+lo) into LDS ----
  for (int ci = tid; ci < 8192; ci += 512) {
    int plane = ci >> 12, rem = ci & 4095;
    int n = rem >> 7, ch = rem & 127;
    int wrow = (n >> 3) * 1024 + u0 + (n & 7);
    const u16* src = (plane ? Wlo : Whi) + (size_t)wrow * 1024 + ch * 8;
    *(u16x8*)&sW[plane * 33024 + n * 1032 + ch * 8] = *(const u16x8*)src;
  }
  __syncthreads();

  const int mt = wv >> 1, kh = wv & 1;        // m-tile (16 batches), k-half (512)
  const int aoff = (mt * 16 + l15) * 1024 + kh * 512 + l4 * 8;
  const int bof0 = l15 * 1032 + kh * 512 + l4 * 8;
  const int bof1 = (16 + l15) * 1032 + kh * 512 + l4 * 8;

  // poll set: producer waves {2mt, 2mt+1} over blocks {kh*64 + lane}
  const u32* f0a = flg + (2 * mt) * 128 + kh * 64 + lane;
  const u32* f0b = flg + (2 * mt + 1) * 128 + kh * 64 + lane;
  u32* fown = flg + wv * 128 + ublk;

  // pointwise cell: batch pb (0..63), unit uu (0..7)
  const int pb = tid >> 3, uu = tid & 7;
  const int cidx = pb * 1024 + u0 + uu;
  float c = cbp[cidx];
  const float* xgb = xg + (size_t)ublk * 131072 + pb * 8 + uu;

  for (int t = 0; t < TC; ++t) {
    // ---- xg prefetch (produced by an earlier dispatch; safe pre-wait) ----
    float px0, px1, px2, px3;
    {
      const float* xa = xgb + (size_t)t * 2048;
      asm volatile("global_load_dword %0, %1, off" : "=v"(px0) : "v"(xa));
      asm volatile("global_load_dword %0, %1, off" : "=v"(px1) : "v"(xa + 512));
      asm volatile("global_load_dword %0, %1, off" : "=v"(px2) : "v"(xa + 1024));
      asm volatile("global_load_dword %0, %1, off" : "=v"(px3) : "v"(xa + 1536));
    }

    // ---- per-wave poll of own-half producer waves ----
    if (t > 0 && *(volatile int*)&sDead == 0) {
      int guard = 0;
      for (;;) {
        u32 a = __hip_atomic_load(f0a, __ATOMIC_RELAXED, __HIP_MEMORY_SCOPE_AGENT);
        u32 b = __hip_atomic_load(f0b, __ATOMIC_RELAXED, __HIP_MEMORY_SCOPE_AGENT);
        if (a >= (u32)t && b >= (u32)t) break;
        if (++guard > (1 << 17)) { if (lane == 0) sDead = 1; break; }
        __builtin_amdgcn_s_sleep(1);
      }
    }

    // ---- recurrent matmul over this wave's k-half ----
    const u16* oah = (t ? ringH + (size_t)(t - 1) * 65536 : carryH) + aoff;
    const u16* oal = (t ? ringL + (size_t)(t - 1) * 65536 : carryL) + aoff;
    f32x4 aq[2][2] = {};   // [nt][kc parity]
#pragma unroll
    for (int kc = 0; kc < 16; ++kc) {
      const int ko = kc * 32;
      u16x8 oh = *(const u16x8*)(oah + ko);
      u16x8 ol = *(const u16x8*)(oal + ko);
      u16x8 b0h = *(const u16x8*)&sW[bof0 + ko];
      u16x8 b0l = *(const u16x8*)&sW[33024 + bof0 + ko];
      u16x8 b1h = *(const u16x8*)&sW[bof1 + ko];
      u16x8 b1l = *(const u16x8*)&sW[33024 + bof1 + ko];
      aq[0][kc & 1] = mfma16(oh, b0h, aq[0][kc & 1]);
      aq[0][kc & 1] = mfma16(ol, b0h, aq[0][kc & 1]);
      aq[0][kc & 1] = mfma16(oh, b0l, aq[0][kc & 1]);
      aq[1][kc & 1] = mfma16(oh, b1h, aq[1][kc & 1]);
      aq[1][kc & 1] = mfma16(ol, b1h, aq[1][kc & 1]);
      aq[1][kc & 1] = mfma16(oh, b1l, aq[1][kc & 1]);
    }
    f32x4 A0 = aq[0][0] + aq[0][1];
    f32x4 A1 = aq[1][0] + aq[1][1];

    __syncthreads();   // prev round's sg fully consumed
#pragma unroll
    for (int r4 = 0; r4 < 4; ++r4) {
      int m = mt * 16 + l4 * 4 + r4;
      sg[kh][m][l15] = A0[r4];
      sg[kh][m][16 + l15] = A1[r4];
    }
    __syncthreads();   // sg ready

    // ---- pointwise on all 512 threads ----
    float g0 = sg[0][pb][uu] + sg[1][pb][uu];
    float g1 = sg[0][pb][8 + uu] + sg[1][pb][8 + uu];
    float g2 = sg[0][pb][16 + uu] + sg[1][pb][16 + uu];
    float g3 = sg[0][pb][24 + uu] + sg[1][pb][24 + uu];
    waitcnt0();  // px ready
    g0 += px0; g1 += px1; g2 += px2; g3 += px3;
    c = sigmoidf_(g1) * c + sigmoidf_(g0) * tanhf(g2);
    float h = sigmoidf_(g3) * tanhf(c);
    u32 hiu = (u32)f2bf(h);
    u32 lou = (u32)f2bf(h - bf2f((u16)hiu));
    u32 hiN = __shfl_down(hiu, 1);
    u32 loN = __shfl_down(lou, 1);
    if ((tid & 1) == 0) {
      size_t re = (size_t)t * 65536 + (size_t)pb * 1024 + u0 + uu;
      store4_cc(ringH + re, hiu | (hiN << 16));
      store4_cc(ringL + re, lou | (loN << 16));
      if (t == TC - 1) {
        store4_cc(carryH + cidx, hiu | (hiN << 16));
        store4_cc(carryL + cidx, lou | (loN << 16));
      }
    }
    if (hfinal && t == TC - 1) hfinal[cidx] = h;

    // ---- drain own wave's stores, raise own flag ----
    waitcnt0();
    if (lane == 0) store4_cc_u32(fown, (u32)(t + 1));
  }

  cbp[cidx] = c;
}

// ---------- MLP (fp32 vector) ----------
__global__ void k_fc(const float* __restrict__ in, const float* __restrict__ W,
                     const float* __restrict__ bias, float* __restrict__ out,
                     int K, int N, int relu) {
  int b = blockIdx.x;
  int n = blockIdx.y * 256 + threadIdx.x;
  if (n >= N) return;
  const float4* wr = (const float4*)(W + (size_t)n * K);
  const float4* xr = (const float4*)(in + (size_t)b * K);
  float s = 0.f;
  for (int k = 0; k < K / 4; ++k) {
    float4 w = wr[k], x = xr[k];
    s += w.x * x.x + w.y * x.y + w.z * x.z + w.w * x.w;
  }
  s += bias[n];
  if (relu) s = fmaxf(s, 0.f);
  out[(size_t)b * N + n] = s;
}

__global__ void k_out(const float* __restrict__ z, const float* __restrict__ W3,
                      const float* __restrict__ b3, float* __restrict__ outp) {
  int b = blockIdx.x;
  int lane = threadIdx.x;  // 64
  const float4* wr = (const float4*)W3;
  const float4* xr = (const float4*)(z + b * 512);
  float s = 0.f;
  for (int k = lane; k < 128; k += 64) {
    float4 w = wr[k], x = xr[k];
    s += w.x * x.x + w.y * x.y + w.z * x.z + w.w * x.w;
  }
  for (int off = 32; off; off >>= 1) s += __shfl_down(s, off);
  if (lane == 0) outp[b] = s + b3[0];
}

// ---------- launch ----------
extern "C" void kernel_launch(void* const* d_in, const int* in_sizes, int n_in,
                              void* d_out, int out_size, void* d_ws, size_t ws_size,
                              hipStream_t stream) {
  (void)in_sizes; (void)n_in; (void)out_size; (void)ws_size;
  const float* xx  = (const float*)d_in[0];
  const float* W10 = (const float*)d_in[1];
  const float* b10i = (const float*)d_in[2];
  const float* b10h = (const float*)d_in[3];
  const float* W11 = (const float*)d_in[4];
  const float* b11i = (const float*)d_in[5];
  const float* b11h = (const float*)d_in[6];
  const float* W20 = (const float*)d_in[7];
  const float* Wh0 = (const float*)d_in[8];
  const float* b20i = (const float*)d_in[9];
  const float* b20h = (const float*)d_in[10];
  const float* W21 = (const float*)d_in[11];
  const float* Wh1 = (const float*)d_in[12];
  const float* b21i = (const float*)d_in[13];
  const float* b21h = (const float*)d_in[14];
  const float* mW1 = (const float*)d_in[15];
  const float* mb1 = (const float*)d_in[16];
  const float* mW2 = (const float*)d_in[17];
  const float* mb2 = (const float*)d_in[18];
  const float* mW3 = (const float*)d_in[19];
  const float* mb3 = (const float*)d_in[20];

  char* ws = (char*)d_ws;
  size_t o = 0;
  float* XG0 = (float*)(ws + o); o += (size_t)MC * G4 * 4;           // 64 MiB (l1 xg + l2-0 gates)
  float* XG1 = (float*)(ws + o); o += (size_t)MC * G4 * 4;           // 64 MiB (l2-1 gates)
  u16* Aah = (u16*)(ws + o); o += (size_t)MC * H_ * 2;               // l1 ping / h1 ring
  u16* Aal = (u16*)(ws + o); o += (size_t)MC * H_ * 2;
  u16* Abh = (u16*)(ws + o); o += (size_t)MC * H_ * 2;               // l1 pong / h0 ring
  u16* Abl = (u16*)(ws + o); o += (size_t)MC * H_ * 2;
  u16* XXh = (u16*)(ws + o); o += (size_t)MC * D_ * 2;
  u16* XXl = (u16*)(ws + o); o += (size_t)MC * D_ * 2;
  u16* W10h = (u16*)(ws + o); o += (size_t)G4 * D_ * 2;
  u16* W10l = (u16*)(ws + o); o += (size_t)G4 * D_ * 2;
  u16* W11h = (u16*)(ws + o); o += (size_t)G4 * H_ * 2;
  u16* W11l = (u16*)(ws + o); o += (size_t)G4 * H_ * 2;
  u16* W20h = (u16*)(ws + o); o += (size_t)G4 * H_ * 2;
  u16* W20l = (u16*)(ws + o); o += (size_t)G4 * H_ * 2;
  u16* Wh0h = (u16*)(ws + o); o += (size_t)G4 * H_ * 2;
  u16* Wh0l = (u16*)(ws + o); o += (size_t)G4 * H_ * 2;
  u16* W21h = (u16*)(ws + o); o += (size_t)G4 * H_ * 2;
  u16* W21l = (u16*)(ws + o); o += (size_t)G4 * H_ * 2;
  u16* Wh1h = (u16*)(ws + o); o += (size_t)G4 * H_ * 2;
  u16* Wh1l = (u16*)(ws + o); o += (size_t)G4 * H_ * 2;
  float* bs0 = (float*)(ws + o); o += G4 * 4;
  float* bs1 = (float*)(ws + o); o += G4 * 4;
  float* bs2 = (float*)(ws + o); o += G4 * 4;
  float* bs3 = (float*)(ws + o); o += G4 * 4;
  // state region (zeroed once per launch, contiguous)
  char* ST = ws + o;
  u16* h00H = (u16*)(ws + o); o += B_ * H_ * 2;
  u16* h00L = (u16*)(ws + o); o += B_ * H_ * 2;
  u16* h01H = (u16*)(ws + o); o += B_ * H_ * 2;
  u16* h01L = (u16*)(ws + o); o += B_ * H_ * 2;
  float* cb0 = (float*)(ws + o); o += B_ * H_ * 4;
  float* cb1 = (float*)(ws + o); o += B_ * H_ * 4;
  u32* FLG = (u32*)(ws + o); o += (NCHUNK + 1) * NFLG * 4;
  size_t stBytes = (size_t)((ws + o) - ST);
  float* FH = (float*)(ws + o); o += B_ * H_ * 4;
  float* Z1 = (float*)(ws + o); o += B_ * H_ * 4;
  float* Z2 = (float*)(ws + o); o += B_ * 512 * 4;

  // rings alias the l1 ping/pong buffers (lifetimes verified: ring0=Ab is
  // consumed by the XG1 GEMM before pw rewrites Ab; ring1=Aa is dead before
  // pw rewrites Aa).
  u16 *r0H = Abh, *r0L = Abl, *r1H = Aah, *r1L = Aal;

  // --- one-time weight/bias prep ---
  k_split<<<(G4 * D_ / 4 + 255) / 256, 256, 0, stream>>>(W10, W10h, W10l, G4 * D_ / 4);
  k_split<<<(G4 * H_ / 4 + 255) / 256, 256, 0, stream>>>(W11, W11h, W11l, G4 * H_ / 4);
  k_split<<<(G4 * H_ / 4 + 255) / 256, 256, 0, stream>>>(W20, W20h, W20l, G4 * H_ / 4);
  k_split<<<(G4 * H_ / 4 + 255) / 256, 256, 0, stream>>>(Wh0, Wh0h, Wh0l, G4 * H_ / 4);
  k_split<<<(G4 * H_ / 4 + 255) / 256, 256, 0, stream>>>(W21, W21h, W21l, G4 * H_ / 4);
  k_split<<<(G4 * H_ / 4 + 255) / 256, 256, 0, stream>>>(Wh1, Wh1h, Wh1l, G4 * H_ / 4);
  k_addvec<<<16, 256, 0, stream>>>(b10i, b10h, bs0, G4);
  k_addvec<<<16, 256, 0, stream>>>(b11i, b11h, bs1, G4);
  k_addvec<<<16, 256, 0, stream>>>(b20i, b20h, bs2, G4);
  k_addvec<<<16, 256, 0, stream>>>(b21i, b21h, bs3, G4);
  hipMemsetAsync(ST, 0, stBytes, stream);

  dim3 gg(MC / 128, G4 / 128);
  const int pwBlocks = MC * H_ / 256;

  for (int c = 0; c < NCHUNK; ++c) {
    int t0 = c * TC;
    k_split_x<<<(MC * (D_ / 4) + 255) / 256, 256, 0, stream>>>(xx, XXh, XXl, t0);
    // l1 layer 0
    k_gemm3<<<gg, 256, 0, stream>>>(XXh, XXl, W10h, W10l, bs0, XG0, MC, G4, D_, 0);
    k_pw<<<pwBlocks, 256, 0, stream>>>(XG0, Aah, Aal);
    // l1 layer 1
    k_gemm3<<<gg, 256, 0, stream>>>(Aah, Aal, W11h, W11l, bs1, XG0, MC, G4, H_, 0);
    k_pw<<<pwBlocks, 256, 0, stream>>>(XG0, Abh, Abl);
    // l2-0 gates (rec layout, A rows b-major = l1 output)
    k_gemm3<<<gg, 256, 0, stream>>>(Abh, Abl, W20h, W20l, bs2, XG0, MC, G4, H_, 1);
    // dual dispatch: rec0(c) [half A] || rec1(c-1) [half B]
    k_recd<<<256, 512, 0, stream>>>(XG0, (c > 0) ? XG1 : nullptr,
                                    Wh0h, Wh0l, Wh1h, Wh1l,
                                    r0H, r0L, r1H, r1L,
                                    h00H, h00L, h01H, h01L, cb0, cb1,
                                    nullptr, FLG + c * NFLG);
    // l2-1 gates from the fresh h0 ring (rec layout, A rows t-major)
    k_gemm3<<<gg, 256, 0, stream>>>(r0H, r0L, W21h, W21l, bs3, XG1, MC, G4, H_, 2);
  }
  // tail: rec1(NCHUNK-1) alone [half B], writes FH
  k_recd<<<256, 512, 0, stream>>>(nullptr, XG1,
                                  Wh0h, Wh0l, Wh1h, Wh1l,
                                  r0H, r0L, r1H, r1L,
                                  h00H, h00L, h01H, h01L, cb0, cb1,
                                  FH, FLG + NCHUNK * NFLG);

  // MLP
  k_fc<<<dim3(B_, 4), 256, 0, stream>>>(FH, mW1, mb1, Z1, H_, H_, 1);
  k_fc<<<dim3(B_, 2), 256, 0, stream>>>(Z1, mW2, mb2, Z2, H_, 512, 1);
  k_out<<<B_, 64, 0, stream>>>(Z2, mW3, mb3, (float*)d_out);
}